// Round 10
// baseline (378.987 us; speedup 1.0000x reference)
//
#include <hip/hip_runtime.h>
#include <stdint.h>

#define IN_C 128
#define OUT_C 64
#define NEG_SLOPE 0.2f
#define RB 256      // blocks in coarse-partition kernels
#define RBINS 512   // coarse bins (node>>8, node<131072)
#define STAGE 8192  // per-bucket LDS staging capacity
#define NGH (RBINS * RB)       // 131072 (tgt histogram)
#define NGHS (RBINS * RBINS)   // 262144 (src histogram)

typedef unsigned int u32;
typedef unsigned long long u64;

// ---------------- helpers ----------------
__device__ __forceinline__ u32 fenc(float f) {
  u32 u = __float_as_uint(f);
  return (u & 0x80000000u) ? ~u : (u | 0x80000000u);
}
__device__ __forceinline__ u64 key64(float v, int i) {
  return (((u64)fenc(v)) << 32) | (u64)(0xffffffffu - (u32)i);
}

// ---------------- h = x @ W + fused ai/aj: LDS-free, barrier-free ----------------
// thread = 4 rows x 8 cols. x,w straight from global (w L1/L2-resident broadcast).
// 782 blocks x 4 waves = 12.2 waves/CU; zero barriers -> waves fully independent.
__global__ __launch_bounds__(256) void k_gemm(const float* __restrict__ x,
                                              const float* __restrict__ w,
                                              const float* __restrict__ att,
                                              float* __restrict__ h,
                                              float* __restrict__ ai, float* __restrict__ aj,
                                              int N) {
  int tid = threadIdx.x;
  int cg = tid & 7, rq = tid >> 3;          // cg: col group, rq: 0..31 row quad
  int c0 = cg * 8;
  int rbase = blockIdx.x * 128 + rq * 4;
  int r[4];
#pragma unroll
  for (int i = 0; i < 4; ++i) r[i] = min(rbase + i, N - 1);  // clamp (stores guarded)

  float acc[4][8];
#pragma unroll
  for (int i = 0; i < 4; i++)
#pragma unroll
    for (int j = 0; j < 8; j++) acc[i][j] = 0.f;

  for (int kb = 0; kb < IN_C; kb += 8) {
    float xr8[4][8];
#pragma unroll
    for (int i = 0; i < 4; ++i) {
      const float4* xp = (const float4*)&x[(size_t)r[i] * IN_C + kb];
      float4 va = xp[0], vb = xp[1];
      *(float4*)&xr8[i][0] = va;
      *(float4*)&xr8[i][4] = vb;
    }
#pragma unroll
    for (int kl = 0; kl < 8; ++kl) {
      float wv[8];
      const float4* wp = (const float4*)&w[(size_t)(kb + kl) * OUT_C + c0];
      *(float4*)&wv[0] = wp[0];
      *(float4*)&wv[4] = wp[1];
#pragma unroll
      for (int i = 0; i < 4; ++i)
#pragma unroll
        for (int j = 0; j < 8; ++j)
          acc[i][j] += xr8[i][kl] * wv[j];
    }
  }

  float pi[4], pj[4];
#pragma unroll
  for (int i = 0; i < 4; ++i) { pi[i] = 0.f; pj[i] = 0.f; }
#pragma unroll
  for (int j = 0; j < 8; ++j) {
    float a0 = att[c0 + j], a1 = att[OUT_C + c0 + j];
#pragma unroll
    for (int i = 0; i < 4; ++i) {
      pi[i] += acc[i][j] * a0;
      pj[i] += acc[i][j] * a1;
    }
  }
#pragma unroll
  for (int o = 1; o < 8; o <<= 1) {
#pragma unroll
    for (int i = 0; i < 4; ++i) {
      pi[i] += __shfl_xor(pi[i], o);
      pj[i] += __shfl_xor(pj[i], o);
    }
  }
#pragma unroll
  for (int i = 0; i < 4; ++i) {
    int row = rbase + i;
    if (row < N) {
      *(float4*)&h[(size_t)row * OUT_C + c0]     = make_float4(acc[i][0], acc[i][1], acc[i][2], acc[i][3]);
      *(float4*)&h[(size_t)row * OUT_C + c0 + 4] = make_float4(acc[i][4], acc[i][5], acc[i][6], acc[i][7]);
      if (cg == 0) { ai[row] = pi[i]; aj[row] = pj[i]; }
    }
  }
}

// ---------------- coarse hist by tgt>>8 + fused select-state init ----------------
__global__ __launch_bounds__(256) void k_rhist_t(const int* __restrict__ tgt,
                                                 int E, int EN, int chunk, u32* __restrict__ gh,
                                                 u32* __restrict__ hist8, u32* __restrict__ done,
                                                 u32* __restrict__ sel, u32* __restrict__ cnt, u32 k) {
  __shared__ u32 lh[RBINS];
  int tid = threadIdx.x, b = blockIdx.x;
  if (b == 0) {
    for (int i = tid; i < 2048; i += 256) hist8[i] = 0u;
    if (tid < 8) { done[tid] = 0u; cnt[tid] = 0u; }
    if (tid == 0) { sel[0] = 0u; sel[1] = 0u; sel[2] = k; sel[3] = 0u; }
  }
  for (int d = tid; d < RBINS; d += 256) lh[d] = 0u;
  __syncthreads();
  int lo = b * chunk, hi = min(lo + chunk, EN);
  for (int e = lo + tid; e < hi; e += 256) {
    int t = (e < E) ? tgt[e] : e - E;
    atomicAdd(&lh[((u32)t) >> 8], 1u);
  }
  __syncthreads();
  for (int d = tid; d < RBINS; d += 256) gh[d * RB + b] = lh[d];
}

// ---------------- 2-kernel scan (block-exclusive + block-sum scan); consumers fold bsum ----------------
__global__ __launch_bounds__(256) void k_scanA(u32* __restrict__ data, u32* __restrict__ bsum, int n) {
  __shared__ u32 s[256];
  int i = blockIdx.x * 256 + threadIdx.x;
  u32 v = (i < n) ? data[i] : 0u;
  s[threadIdx.x] = v;
  __syncthreads();
  for (int o = 1; o < 256; o <<= 1) {
    u32 t = (threadIdx.x >= (unsigned)o) ? s[threadIdx.x - o] : 0u;
    __syncthreads();
    s[threadIdx.x] += t;
    __syncthreads();
  }
  if (i < n) data[i] = s[threadIdx.x] - v;            // exclusive within block
  if (threadIdx.x == 255) bsum[blockIdx.x] = s[255];
}

__global__ __launch_bounds__(1024) void k_scanB(u32* __restrict__ bsum, int nb) {
  __shared__ u32 s[1024];
  int tid = threadIdx.x;
  u32 v = (tid < nb) ? bsum[tid] : 0u;
  s[tid] = v;
  __syncthreads();
  for (int o = 1; o < 1024; o <<= 1) {
    u32 t = (tid >= o) ? s[tid - o] : 0u;
    __syncthreads();
    s[tid] += t;
    __syncthreads();
  }
  if (tid < nb) bsum[tid] = s[tid] - v;               // exclusive block offsets
}

// ---------------- coarse scatter by tgt>>8: u32 items ((tgt&255)<<24 | src) ----------------
__global__ __launch_bounds__(256) void k_rscatter_t(const int* __restrict__ src, const int* __restrict__ tgt,
                                                    int E, int EN, int chunk,
                                                    const u32* __restrict__ gh, const u32* __restrict__ bsumT,
                                                    u32* __restrict__ bufB) {
  __shared__ u32 cnt[RBINS];
  int tid = threadIdx.x, b = blockIdx.x;
  for (int d = tid; d < RBINS; d += 256) cnt[d] = gh[d * RB + b] + bsumT[d];
  __syncthreads();
  int lo = b * chunk, hi = min(lo + chunk, EN);
  for (int e = lo + tid; e < hi; e += 256) {
    int s, t;
    if (e < E) { s = src[e]; t = tgt[e]; } else { s = t = e - E; }
    u32 p = atomicAdd(&cnt[((u32)t) >> 8], 1u);
    bufB[p] = (((u32)t & 255u) << 24) | (u32)s;
  }
}

// ---------------- fine partition + CSR offsets + fused src>>8 hist + FUSED SOFTMAX ----
__global__ __launch_bounds__(256) void k_rpass2(const u32* __restrict__ in, u32* __restrict__ out,
                                                const u32* __restrict__ gh, const u32* __restrict__ bsumT,
                                                u32* __restrict__ ghs,
                                                u32* __restrict__ offT,
                                                const float* __restrict__ ai, const float* __restrict__ aj,
                                                float* __restrict__ alpha,
                                                int N, int EN) {
  __shared__ u32 hist[256];
  __shared__ u32 sc[256];
  __shared__ u32 lhs[RBINS];
  __shared__ u32 stage[STAGE];
  int tid = threadIdx.x, d = blockIdx.x;
  u32 start = gh[d * RB] + bsumT[d];
  u32 end = (d < RBINS - 1) ? (gh[(d + 1) * RB] + bsumT[d + 1]) : (u32)EN;
  int sz = (int)(end - start);
  hist[tid] = 0u;
  for (int dd = tid; dd < RBINS; dd += 256) lhs[dd] = 0u;
  __syncthreads();
  for (u32 p = start + tid; p < end; p += 256) {
    u32 it = in[p];
    atomicAdd(&hist[it >> 24], 1u);
    atomicAdd(&lhs[(it & 0xffffffu) >> 8], 1u);
  }
  __syncthreads();
  for (int dd = tid; dd < RBINS; dd += 256) ghs[dd * RBINS + d] = lhs[dd];
  u32 hv = hist[tid];
  sc[tid] = hv;
  __syncthreads();
  for (int o = 1; o < 256; o <<= 1) {
    u32 t = (tid >= o) ? sc[tid - o] : 0u;
    __syncthreads();
    sc[tid] += t;
    __syncthreads();
  }
  u32 excl = sc[tid] - hv;
  int node = (d << 8) + tid;
  if (node < N) offT[node] = start + excl;
  if (node == 0) offT[N] = (u32)EN;
  hist[tid] = excl;
  __syncthreads();
  bool staged = (sz <= STAGE);
  for (u32 p = start + tid; p < end; p += 256) {
    u32 it = in[p];
    u32 lp = atomicAdd(&hist[it >> 24], 1u);
    if (staged) stage[lp] = it;
    else out[start + lp] = it;
  }
  __syncthreads();
  if (staged)
    for (int i = tid; i < sz; i += 256) out[start + i] = stage[i];
  __syncthreads();
  if (node < N) {
    int lb = (tid > 0) ? (int)sc[tid - 1] : 0;
    int le = (int)sc[tid];
    float an = ai[node];
    float mx = -1e30f;
    for (int i = lb; i < le; ++i) {
      u32 it = staged ? stage[i] : out[start + i];
      float a = an + aj[it & 0xffffffu];
      a = a > 0.f ? a : NEG_SLOPE * a;
      mx = fmaxf(mx, a);
      if (staged) stage[i] = __float_as_uint(a);
    }
    float sm = 0.f;
    for (int i = lb; i < le; ++i) {
      float a;
      if (staged) a = __uint_as_float(stage[i]);
      else {
        u32 it = out[start + i];
        a = an + aj[it & 0xffffffu];
        a = a > 0.f ? a : NEG_SLOPE * a;
      }
      float v = expf(a - mx);
      sm += v;
      if (staged) stage[i] = __float_as_uint(v);
      else alpha[start + i] = v;
    }
    float inv = 1.f / (sm + 1e-16f);
    for (int i = lb; i < le; ++i) {
      float v = staged ? __uint_as_float(stage[i]) : alpha[start + i];
      alpha[start + i] = v * inv;
    }
  }
}

// ---------------- scatter by src>>8 over the SAME per-bucket ranges as k_rpass2 ----------------
__global__ __launch_bounds__(256) void k_rscatter_s(const u32* __restrict__ csr,
                                                    const float* __restrict__ alpha,
                                                    const u32* __restrict__ gh, const u32* __restrict__ bsumT,
                                                    const u32* __restrict__ ghs, const u32* __restrict__ bsumS,
                                                    u64* __restrict__ bufB, int EN) {
  __shared__ u32 cnt[RBINS];
  int tid = threadIdx.x, d = blockIdx.x;
  for (int dd = tid; dd < RBINS; dd += 256)
    cnt[dd] = ghs[dd * RBINS + d] + bsumS[dd * 2 + (d >> 8)];
  __syncthreads();
  u32 start = gh[d * RB] + bsumT[d];
  u32 end = (d < RBINS - 1) ? (gh[(d + 1) * RB] + bsumT[d + 1]) : (u32)EN;
  for (u32 e = start + tid; e < end; e += 256) {
    u32 s = csr[e] & 0xffffffu;
    u32 p = atomicAdd(&cnt[s >> 8], 1u);
    bufB[p] = (((u64)(s & 255u)) << 32) | __float_as_uint(alpha[e]);
  }
}

// ---------------- per-bucket alpha_sum + FUSED select pass 0 ----------------
__global__ __launch_bounds__(256) void k_asum_acc(const u64* __restrict__ bufB,
                                                  const u32* __restrict__ ghs, const u32* __restrict__ bsumS,
                                                  float* __restrict__ asum,
                                                  u32* __restrict__ hist8, u32* __restrict__ done,
                                                  u32* __restrict__ sel,
                                                  int N, int EN) {
  __shared__ float sums[256];
  __shared__ u32 lh[256];
  __shared__ u32 s[256];
  __shared__ u32 sres;
  int tid = threadIdx.x, d = blockIdx.x;
  u32 start = ghs[d * RBINS] + bsumS[d * 2];
  u32 end = (d < RBINS - 1) ? (ghs[(d + 1) * RBINS] + bsumS[(d + 1) * 2]) : (u32)EN;
  sums[tid] = 0.f;
  lh[tid] = 0u;
  __syncthreads();
  for (u32 p = start + tid; p < end; p += 256) {
    u64 it = bufB[p];
    atomicAdd(&sums[(u32)(it >> 32)], __uint_as_float((u32)it));
  }
  __syncthreads();
  int node = d * 256 + tid;
  float myv = sums[tid];
  if (node < N) {
    asum[node] = myv;
    // select pass 0: top byte of fenc
    atomicAdd(&lh[fenc(myv) >> 24], 1u);
  }
  __syncthreads();
  if (lh[tid]) atomicAdd(&hist8[tid], lh[tid]);
  __syncthreads();
  if (tid == 0)
    sres = __hip_atomic_fetch_add(&done[0], 1u, __ATOMIC_ACQ_REL, __HIP_MEMORY_SCOPE_AGENT);
  __syncthreads();
  if (sres == (u32)(RBINS - 1)) {    // last block: pick digit 0
    u32 krem = sel[2];
    u32 hv = __hip_atomic_load(&hist8[255 - tid], __ATOMIC_RELAXED, __HIP_MEMORY_SCOPE_AGENT);
    s[tid] = hv;
    __syncthreads();
    for (int o = 1; o < 256; o <<= 1) {
      u32 t = (tid >= o) ? s[tid - o] : 0u;
      __syncthreads();
      s[tid] += t;
      __syncthreads();
    }
    u32 cum = s[tid], prev = (tid > 0) ? s[tid - 1] : 0u;
    if (cum >= krem && prev < krem) {
      ((u64*)sel)[0] = (u64)(u32)(255 - tid);
      sel[2] = krem - prev;
    }
  }
}

// ---------------- fused radix-select pass (1..3): hist + append + last-block pick (+finish) ----------------
__global__ __launch_bounds__(256) void k_histpick(const float* __restrict__ asum,
                                                  const u32* __restrict__ list_in, const u32* __restrict__ cnt_in,
                                                  u32* __restrict__ list_out, u32* __restrict__ cnt_out,
                                                  u32* __restrict__ hist8, u32* __restrict__ done,
                                                  u32* __restrict__ sel, int N, int pass, int nblk,
                                                  int do_finish) {
  __shared__ u32 lh[256];
  __shared__ u32 sres;
  __shared__ u32 s[256];
  __shared__ u32 sfin[2];
  __shared__ u64 keys[2048];
  __shared__ u32 cc;
  int tid = threadIdx.x;
  lh[tid] = 0u;
  __syncthreads();
  u64 prefix = ((const u64*)sel)[0];
  int shift = 56 - 8 * pass;
  int n = list_in ? (int)*cnt_in : N;
  int i = blockIdx.x * 256 + tid;
  if (i < n) {
    int idx = list_in ? (int)list_in[i] : i;
    u64 k = key64(asum[idx], idx);
    if ((k >> (shift + 8)) == prefix) {
      atomicAdd(&lh[(u32)(k >> shift) & 255u], 1u);
      if (list_out) {
        u32 p = atomicAdd(cnt_out, 1u);
        list_out[p] = (u32)idx;
      }
    }
  }
  __syncthreads();
  if (lh[tid]) atomicAdd(&hist8[pass * 256 + tid], lh[tid]);
  __syncthreads();
  if (tid == 0)
    sres = __hip_atomic_fetch_add(&done[pass], 1u, __ATOMIC_ACQ_REL, __HIP_MEMORY_SCOPE_AGENT);
  __syncthreads();
  if (sres == (u32)(nblk - 1)) {
    u32 krem = sel[2];
    u32 hv = __hip_atomic_load(&hist8[pass * 256 + (255 - tid)], __ATOMIC_RELAXED,
                               __HIP_MEMORY_SCOPE_AGENT);
    s[tid] = hv;
    __syncthreads();
    for (int o = 1; o < 256; o <<= 1) {
      u32 t = (tid >= o) ? s[tid - o] : 0u;
      __syncthreads();
      s[tid] += t;
      __syncthreads();
    }
    u32 cum = s[tid], prev = (tid > 0) ? s[tid - 1] : 0u;
    if (cum >= krem && prev < krem) {
      int dsel = 255 - tid;
      ((u64*)sel)[0] = (prefix << 8) | (u64)(u32)dsel;
      sel[2] = krem - prev;
      sfin[0] = (u32)dsel;
      sfin[1] = krem - prev;
    }
    if (do_finish) {
      __syncthreads();
      u32 fsel = (u32)((prefix << 8) | (u64)sfin[0]);
      u32 krem2 = sfin[1];
      if (tid == 0) cc = 0u;
      __syncthreads();
      int n3 = (int)__hip_atomic_load(cnt_out, __ATOMIC_RELAXED, __HIP_MEMORY_SCOPE_AGENT);
      for (int q = tid; q < n3; q += 256) {
        int idx = (int)list_out[q];
        u64 k = key64(asum[idx], idx);
        if ((u32)(k >> 32) == fsel) {
          u32 p = atomicAdd(&cc, 1u);
          if (p < 2048) keys[p] = k;
        }
      }
      __syncthreads();
      int C = (int)min(cc, 2048u);
      for (int q = tid; q < C; q += 256) {
        u64 k = keys[q];
        u32 rank = 0;
        for (int j = 0; j < C; ++j)
          if (keys[j] > k) rank++;
        if (rank == krem2 - 1) ((u64*)sel)[0] = k;   // full 64-bit threshold key
      }
    }
  }
}

// ---------------- masks output: out_edge (raw order) + out_node; no aux arrays ----------------
__global__ __launch_bounds__(256) void k_masks(const int* __restrict__ src, const int* __restrict__ tgt,
                                               const float* __restrict__ asum, const u32* __restrict__ sel,
                                               float* __restrict__ out_edge, float* __restrict__ out_node,
                                               int E, int EN, int N) {
  int e = blockIdx.x * 256 + threadIdx.x;
  if (e >= EN) return;
  u64 T = ((const u64*)sel)[0];
  int s, t;
  if (e < E) { s = src[e]; t = tgt[e]; } else { s = t = e - E; }
  bool ms = key64(asum[s], s) >= T;
  bool mt = key64(asum[t], t) >= T;
  out_edge[e] = (ms && mt) ? 1.f : 0.f;
  if (e < N) out_node[e] = (key64(asum[e], e) >= T) ? 1.f : 0.f;
}

// ---------------- aggregate: branchless 8-deep, masks from asum, row-0 trick ----------------
__global__ __launch_bounds__(256) void k_aggregate(const u32* __restrict__ off,
                                                   const u32* __restrict__ csr,
                                                   const float* __restrict__ alpha,
                                                   const float* __restrict__ asum,
                                                   const u32* __restrict__ sel,
                                                   const float* __restrict__ h,
                                                   float* __restrict__ out, int N) {
  int node = blockIdx.x * 8 + (threadIdx.x >> 5);
  int sub = threadIdx.x & 31;
  int g = sub >> 4;
  int c = sub & 15;
  if (node >= N) return;
  u64 T = ((const u64*)sel)[0];
  float4 acc = make_float4(0.f, 0.f, 0.f, 0.f);
  if (key64(asum[node], node) >= T) {
    u32 b = off[node], e2 = off[node + 1];
    for (u32 p0 = b; p0 < e2; p0 += 16) {
      float av[8];
      u32 sv[8];
#pragma unroll
      for (int q = 0; q < 8; ++q) {
        u32 p = p0 + q * 2 + (u32)g;
        bool ok = p < e2;
        u32 pp = ok ? p : b;
        u32 sp = csr[pp] & 0xffffffu;
        float a = alpha[pp];
        bool ms = key64(asum[sp], sp) >= T;
        av[q] = (ok && ms) ? a : 0.f;
        sv[q] = ms ? sp : 0u;        // masked -> row 0 (cache-hot, alpha=0)
      }
      float4 hv[8];
#pragma unroll
      for (int q = 0; q < 8; ++q)
        hv[q] = *(const float4*)&h[(size_t)sv[q] * OUT_C + c * 4];
#pragma unroll
      for (int q = 0; q < 8; ++q) {
        acc.x += av[q] * hv[q].x;
        acc.y += av[q] * hv[q].y;
        acc.z += av[q] * hv[q].z;
        acc.w += av[q] * hv[q].w;
      }
    }
    acc.x += __shfl_xor(acc.x, 16);
    acc.y += __shfl_xor(acc.y, 16);
    acc.z += __shfl_xor(acc.z, 16);
    acc.w += __shfl_xor(acc.w, 16);
  }
  if (g == 0)
    *(float4*)&out[(size_t)node * OUT_C + c * 4] = acc;
}

// ---------------- launch ----------------
extern "C" void kernel_launch(void* const* d_in, const int* in_sizes, int n_in,
                              void* d_out, int out_size, void* d_ws, size_t ws_size,
                              hipStream_t stream) {
  const float* x   = (const float*)d_in[0];
  const float* w   = (const float*)d_in[1];
  const float* att = (const float*)d_in[2];
  const int*   ei  = (const int*)d_in[3];

  int N = in_sizes[0] / IN_C;
  int E = in_sizes[3] / 2;
  int EN = E + N;
  const int* src = ei;
  const int* tgt = ei + E;

  float* out      = (float*)d_out;
  float* out_edge = out + (size_t)N * OUT_C;
  float* out_node = out_edge + (size_t)EN;

  char* p = (char*)d_ws;
  auto alloc = [&](size_t bytes) -> char* {
    char* r = p;
    p += (bytes + 255) & ~(size_t)255;
    return r;
  };
  float* h      = (float*)alloc((size_t)N * OUT_C * 4);
  float* ai     = (float*)alloc((size_t)N * 4);
  float* aj     = (float*)alloc((size_t)N * 4);
  u32*   bufA   = (u32*)alloc((size_t)EN * 4);      // CSR items ((tgt&255)<<24 | src)
  u64*   bufB   = (u64*)alloc((size_t)EN * 8);      // partition scratch / src-pairs
  float* alpha  = (float*)alloc((size_t)EN * 4);    // alpha in CSR order
  u32*   offT   = (u32*)alloc((size_t)(N + 1) * 4);
  u32*   gh     = (u32*)alloc((size_t)NGH * 4);     // tgt hist
  u32*   ghs    = (u32*)alloc((size_t)NGHS * 4);    // src hist
  u32*   bsumT  = (u32*)alloc(512 * 4);
  u32*   bsumS  = (u32*)alloc(1024 * 4);
  float* asum   = (float*)alloc((size_t)N * 4);
  u32*   hist8  = (u32*)alloc(2048 * 4);
  u32*   done   = (u32*)alloc(8 * 4);
  u32*   cnt    = (u32*)alloc(8 * 4);
  u32*   sel    = (u32*)alloc(256);
  u32*   listA  = (u32*)alloc((size_t)N * 4);
  u32*   listB  = (u32*)alloc((size_t)N * 4);

  u32 kSel = (u32)((N + 1) / 2);
  int chunk = (EN + RB - 1) / RB;
  int nScanT = (NGH + 255) / 256;    // 512
  int nScanS = (NGHS + 255) / 256;   // 1024
  int gRow = (N + 127) / 128;        // 782
  int gN = (N + 255) / 256;
  int gE = (EN + 255) / 256;
  int gNode8 = (N + 7) / 8;

  k_gemm<<<gRow, 256, 0, stream>>>(x, w, att, h, ai, aj, N);

  // ---- partition by target -> bufA = CSR, offT; fused select-state init ----
  k_rhist_t<<<RB, 256, 0, stream>>>(tgt, E, EN, chunk, gh, hist8, done, sel, cnt, kSel);
  k_scanA<<<nScanT, 256, 0, stream>>>(gh, bsumT, NGH);
  k_scanB<<<1, 1024, 0, stream>>>(bsumT, nScanT);
  k_rscatter_t<<<RB, 256, 0, stream>>>(src, tgt, E, EN, chunk, gh, bsumT, (u32*)bufB);
  k_rpass2<<<RBINS, 256, 0, stream>>>((u32*)bufB, bufA, gh, bsumT, ghs, offT, ai, aj, alpha, N, EN);

  // ---- src partition (hist fused in rpass2) -> alpha_sum; pass0 fused into asum_acc ----
  k_scanA<<<nScanS, 256, 0, stream>>>(ghs, bsumS, NGHS);
  k_scanB<<<1, 1024, 0, stream>>>(bsumS, nScanS);
  k_rscatter_s<<<RBINS, 256, 0, stream>>>(bufA, alpha, gh, bsumT, ghs, bsumS, bufB, EN);
  k_asum_acc<<<RBINS, 256, 0, stream>>>(bufB, ghs, bsumS, asum, hist8, done, sel, N, EN);

  // ---- select passes 1..3 (pass 3 fuses tie-break finish) ----
  k_histpick<<<gN, 256, 0, stream>>>(asum, nullptr, nullptr, listA, &cnt[1],
                                     hist8, done, sel, N, 1, gN, 0);
  k_histpick<<<gN, 256, 0, stream>>>(asum, listA, &cnt[1], listB, &cnt[2],
                                     hist8, done, sel, N, 2, gN, 0);
  k_histpick<<<gN, 256, 0, stream>>>(asum, listB, &cnt[2], listA, &cnt[3],
                                     hist8, done, sel, N, 3, gN, 1);

  k_masks<<<gE, 256, 0, stream>>>(src, tgt, asum, sel, out_edge, out_node, E, EN, N);
  k_aggregate<<<gNode8, 256, 0, stream>>>(offT, bufA, alpha, asum, sel, h, out, N);
}